// Round 6
// baseline (521.626 us; speedup 1.0000x reference)
//
#include <hip/hip_runtime.h>

#define NC 200000
#define NM 50000
#define NE 1000000
#define DF 64   // feature dim (D == H == 64)

#define SCAN_B 512
#define SCAN_T 256

typedef __attribute__((ext_vector_type(8))) short bf16x8;
typedef __attribute__((ext_vector_type(4))) float f32x4;

// ---------------- histogram: bins[dst[e]] += 1 (int atomics) ----------------
__global__ __launch_bounds__(256) void hist_k(const int* __restrict__ dst,
                                              int* __restrict__ bins, int n_edges) {
    int tid = blockIdx.x * blockDim.x + threadIdx.x;
    for (int e = tid; e < n_edges; e += gridDim.x * blockDim.x) {
        atomicAdd(&bins[dst[e]], 1);
    }
}

// ---------------- 3-phase device-wide exclusive scan ----------------
__global__ __launch_bounds__(SCAN_T) void scan_part_k(const int* __restrict__ bins,
                                                      int* __restrict__ partials, int n) {
    __shared__ int red[SCAN_T];
    const int ch = (n + SCAN_B * SCAN_T - 1) / (SCAN_B * SCAN_T);
    const int t = threadIdx.x;
    const long base = ((long)blockIdx.x * SCAN_T + t) * ch;
    int s = 0;
    for (int i = 0; i < ch; ++i) {
        long idx = base + i;
        if (idx < n) s += bins[idx];
    }
    red[t] = s;
    __syncthreads();
    for (int off = SCAN_T / 2; off > 0; off >>= 1) {
        if (t < off) red[t] += red[t + off];
        __syncthreads();
    }
    if (t == 0) partials[blockIdx.x] = red[0];
}

__global__ __launch_bounds__(SCAN_B) void scan_mid_k(const int* __restrict__ partials,
                                                     int* __restrict__ boff,
                                                     int* __restrict__ start, int n) {
    __shared__ int s[SCAN_B];
    const int t = threadIdx.x;
    s[t] = partials[t];
    __syncthreads();
    for (int off = 1; off < SCAN_B; off <<= 1) {
        int v = 0;
        if (t >= off) v = s[t - off];
        __syncthreads();
        if (t >= off) s[t] += v;
        __syncthreads();
    }
    boff[t] = (t == 0) ? 0 : s[t - 1];
    if (t == SCAN_B - 1) start[n] = s[t];
}

__global__ __launch_bounds__(SCAN_T) void scan_fin_k(const int* __restrict__ bins,
                                                     const int* __restrict__ boff,
                                                     int* __restrict__ start, int n) {
    __shared__ int red[SCAN_T];
    const int ch = (n + SCAN_B * SCAN_T - 1) / (SCAN_B * SCAN_T);
    const int t = threadIdx.x;
    const long base = ((long)blockIdx.x * SCAN_T + t) * ch;
    int s = 0;
    for (int i = 0; i < ch; ++i) {
        long idx = base + i;
        if (idx < n) s += bins[idx];
    }
    red[t] = s;
    __syncthreads();
    for (int off = 1; off < SCAN_T; off <<= 1) {
        int v = 0;
        if (t >= off) v = red[t - off];
        __syncthreads();
        if (t >= off) red[t] += v;
        __syncthreads();
    }
    int run = boff[blockIdx.x] + ((t == 0) ? 0 : red[t - 1]);
    for (int i = 0; i < ch; ++i) {
        long idx = base + i;
        if (idx < n) {
            start[idx] = run;
            run += bins[idx];
        }
    }
}

// ---------------- placement: sorted_src[start[d] + cur[d]++] = src[e] ----------------
__global__ __launch_bounds__(256) void place_k(const int* __restrict__ src,
                                               const int* __restrict__ dst,
                                               const int* __restrict__ start,
                                               int* __restrict__ cur,
                                               int* __restrict__ sorted_src, int n_edges) {
    int tid = blockIdx.x * blockDim.x + threadIdx.x;
    for (int e = tid; e < n_edges; e += gridDim.x * blockDim.x) {
        int d = dst[e];
        int pos = start[d] + atomicAdd(&cur[d], 1);
        sorted_src[pos] = src[e];
    }
}

// ---------------- round-to-nearest split-bf16 helpers ----------------
__device__ __forceinline__ short bf16rn(float x) {
    unsigned u = __builtin_bit_cast(unsigned, x);
    unsigned r = u + 0x7FFFu + ((u >> 16) & 1u);
    return (short)(r >> 16);
}
__device__ __forceinline__ float bf16f(short h) {
    unsigned u = ((unsigned)(unsigned short)h) << 16;
    return __builtin_bit_cast(float, u);
}
__device__ __forceinline__ void split8(const f32x4 u, const f32x4 v,
                                       bf16x8& hi, bf16x8& lo) {
#pragma unroll
    for (int b = 0; b < 4; ++b) {
        short h = bf16rn(u[b]);
        hi[b] = h;
        lo[b] = bf16rn(u[b] - bf16f(h));
    }
#pragma unroll
    for (int b = 0; b < 4; ++b) {
        short h = bf16rn(v[b]);
        hi[4 + b] = h;
        lo[4 + b] = bf16rn(v[b] - bf16f(h));
    }
}

#define MFMA(a, b, c) __builtin_amdgcn_mfma_f32_16x16x32_bf16((a), (b), (c), 0, 0, 0)

// 4-term product: acc += (hi+lo)_A * (hi+lo)_B
#define MFMA4(ah, al, bh, bl, acc)      \
    do {                                \
        acc = MFMA(ah, bh, acc);        \
        acc = MFMA(ah, bl, acc);        \
        acc = MFMA(al, bh, acc);        \
        acc = MFMA(al, bl, acc);        \
    } while (0)

// load + split this wave's 16-column weight fragments (K=64 in 2 chunks of 32)
#define LOAD_W(Wl, Wr, col, g, wlh, wll, wrh, wrl)          \
    do {                                                    \
        _Pragma("unroll")                                   \
        for (int q = 0; q < 2; ++q) {                       \
            f32x4 tl0, tl1, tr0, tr1;                       \
            _Pragma("unroll")                               \
            for (int b = 0; b < 4; ++b) {                   \
                int k = 32 * q + 8 * (g) + b;               \
                tl0[b] = (Wl)[k * DF + (col)];              \
                tr0[b] = (Wr)[k * DF + (col)];              \
                tl1[b] = (Wl)[(k + 4) * DF + (col)];        \
                tr1[b] = (Wr)[(k + 4) * DF + (col)];        \
            }                                               \
            split8(tl0, tl1, wlh[q], wll[q]);               \
            split8(tr0, tr1, wrh[q], wrl[q]);               \
        }                                                   \
    } while (0)

// ---- aggregation of one node's neighbor rows, 4 rows (1KB) in flight/instr ----
// 16-lane subgroup `g` handles edges e = s0+g, s0+g+4, ...; lane holds f32x4 at c4.
// After shfl-reduce over subgroups, g==0 lanes hold the mean; write to sArow.
__device__ __forceinline__ void agg_node(const float* __restrict__ xg,
                                         const int* __restrict__ srt,
                                         int s0, int s1, int g, int c4,
                                         float* __restrict__ sArow) {
    f32x4 acc = {0.f, 0.f, 0.f, 0.f};
    for (int e = s0 + g; e < s1; e += 4) {
        const int s = srt[e];
        const f32x4 v = *(const f32x4*)(xg + (long)s * DF + c4);
        acc[0] += v[0]; acc[1] += v[1]; acc[2] += v[2]; acc[3] += v[3];
    }
#pragma unroll
    for (int c = 0; c < 4; ++c) {
        acc[c] += __shfl_xor(acc[c], 16);
        acc[c] += __shfl_xor(acc[c], 32);
    }
    if (g == 0) {
        const float inv = 1.0f / fmaxf((float)(s1 - s0), 1.0f);
        f32x4 m;
        m[0] = acc[0] * inv; m[1] = acc[1] * inv;
        m[2] = acc[2] * inv; m[3] = acc[3] * inv;
        *(f32x4*)(sArow + c4) = m;
    }
}

// ---------------- fused1: h = relu(seg_mean(xg) @ Wl + xdst @ Wr + b) ----------------
// block = 4 waves = one 16-node row tile; wave wv aggregates rows wv*4..+3 into LDS,
// then computes column-tile wv of the MFMA.
__global__ __launch_bounds__(256) void fused1_k(const float* __restrict__ xg,
                                                const int* __restrict__ start,
                                                const int* __restrict__ srt,
                                                const float* __restrict__ xdst,
                                                const float* __restrict__ Wl,
                                                const float* __restrict__ Wr,
                                                const float* __restrict__ bias,
                                                float* __restrict__ hout, int n_nodes) {
    __shared__ float sA[16][68];
    const int t = threadIdx.x;
    const int lane = t & 63;
    const int wv = t >> 6;
    const int col = wv * 16 + (lane & 15);
    const int g = lane >> 4;
    const int c4 = (lane & 15) * 4;

    bf16x8 wlh[2], wll[2], wrh[2], wrl[2];
    LOAD_W(Wl, Wr, col, g, wlh, wll, wrh, wrl);
    const float bv = bias[col];

    const int nrt = n_nodes >> 4;
    for (int rt = blockIdx.x; rt < nrt; rt += gridDim.x) {
        // ---- aggregation phase ----
#pragma unroll
        for (int ni = 0; ni < 4; ++ni) {
            const int row = wv * 4 + ni;
            const int node = rt * 16 + row;
            agg_node(xg, srt, start[node], start[node + 1], g, c4, &sA[row][0]);
        }
        // xdst row fragments straight from global
        const float* xrow = xdst + ((long)rt * 16 + (lane & 15)) * DF + 8 * g;
        const f32x4 xu0 = *(const f32x4*)(xrow + 0);
        const f32x4 xv0 = *(const f32x4*)(xrow + 4);
        const f32x4 xu1 = *(const f32x4*)(xrow + 32);
        const f32x4 xv1 = *(const f32x4*)(xrow + 36);
        __syncthreads();

        // ---- MFMA phase ----
        const int ar = lane & 15;
        const f32x4 au0 = *(const f32x4*)&sA[ar][8 * g + 0];
        const f32x4 av0 = *(const f32x4*)&sA[ar][8 * g + 4];
        const f32x4 au1 = *(const f32x4*)&sA[ar][8 * g + 32];
        const f32x4 av1 = *(const f32x4*)&sA[ar][8 * g + 36];

        f32x4 acc = {0.f, 0.f, 0.f, 0.f};
        bf16x8 h, l;
        split8(au0, av0, h, l);
        MFMA4(h, l, wlh[0], wll[0], acc);
        split8(au1, av1, h, l);
        MFMA4(h, l, wlh[1], wll[1], acc);
        split8(xu0, xv0, h, l);
        MFMA4(h, l, wrh[0], wrl[0], acc);
        split8(xu1, xv1, h, l);
        MFMA4(h, l, wrh[1], wrl[1], acc);

#pragma unroll
        for (int r = 0; r < 4; ++r) {
            float v = fmaxf(acc[r] + bv, 0.0f);
            hout[((long)rt * 16 + 4 * g + r) * DF + col] = v;
        }
        __syncthreads();   // all LDS reads done before next iter's staging
    }
}

// ---------------- fused2: h2 = seg_mean(hg) @ Wl + hc @ Wr + b; out += h2 @ Wlin ----------------
__global__ __launch_bounds__(256) void fused2_k(const float* __restrict__ hg,
                                                const int* __restrict__ start,
                                                const int* __restrict__ srt,
                                                const float* __restrict__ hc,
                                                const float* __restrict__ Wl,
                                                const float* __restrict__ Wr,
                                                const float* __restrict__ bias,
                                                const float* __restrict__ Wlin,
                                                const float* __restrict__ blin,
                                                float* __restrict__ out, int n_nodes) {
    __shared__ float sA[16][68];
    const int t = threadIdx.x;
    const int lane = t & 63;
    const int wv = t >> 6;
    const int col = wv * 16 + (lane & 15);
    const int g = lane >> 4;
    const int c4 = (lane & 15) * 4;

    bf16x8 wlh[2], wll[2], wrh[2], wrl[2];
    LOAD_W(Wl, Wr, col, g, wlh, wll, wrh, wrl);
    const float bv = bias[col];
    const float wl0 = Wlin[col * 2 + 0];
    const float wl1 = Wlin[col * 2 + 1];
    const float bl0 = (wv == 0) ? blin[0] : 0.0f;
    const float bl1 = (wv == 0) ? blin[1] : 0.0f;

    const int nrt = n_nodes >> 4;
    for (int rt = blockIdx.x; rt < nrt; rt += gridDim.x) {
#pragma unroll
        for (int ni = 0; ni < 4; ++ni) {
            const int row = wv * 4 + ni;
            const int node = rt * 16 + row;
            agg_node(hg, srt, start[node], start[node + 1], g, c4, &sA[row][0]);
        }
        const float* hrow = hc + ((long)rt * 16 + (lane & 15)) * DF + 8 * g;
        const f32x4 hu0 = *(const f32x4*)(hrow + 0);
        const f32x4 hv0 = *(const f32x4*)(hrow + 4);
        const f32x4 hu1 = *(const f32x4*)(hrow + 32);
        const f32x4 hv1 = *(const f32x4*)(hrow + 36);
        __syncthreads();

        const int ar = lane & 15;
        const f32x4 au0 = *(const f32x4*)&sA[ar][8 * g + 0];
        const f32x4 av0 = *(const f32x4*)&sA[ar][8 * g + 4];
        const f32x4 au1 = *(const f32x4*)&sA[ar][8 * g + 32];
        const f32x4 av1 = *(const f32x4*)&sA[ar][8 * g + 36];

        f32x4 acc = {0.f, 0.f, 0.f, 0.f};
        bf16x8 h, l;
        split8(au0, av0, h, l);
        MFMA4(h, l, wlh[0], wll[0], acc);
        split8(au1, av1, h, l);
        MFMA4(h, l, wlh[1], wll[1], acc);
        split8(hu0, hv0, h, l);
        MFMA4(h, l, wrh[0], wrl[0], acc);
        split8(hu1, hv1, h, l);
        MFMA4(h, l, wrh[1], wrl[1], acc);

#pragma unroll
        for (int r = 0; r < 4; ++r) {
            float h2 = acc[r] + bv;
            float p0 = h2 * wl0;
            float p1 = h2 * wl1;
#pragma unroll
            for (int m = 1; m < 16; m <<= 1) {
                p0 += __shfl_xor(p0, m);
                p1 += __shfl_xor(p1, m);
            }
            if ((lane & 15) == 0) {
                long node = (long)rt * 16 + 4 * g + r;
                atomicAdd(&out[node * 2 + 0], p0 + bl0);
                atomicAdd(&out[node * 2 + 1], p1 + bl1);
            }
        }
        __syncthreads();
    }
}

extern "C" void kernel_launch(void* const* d_in, const int* in_sizes, int n_in,
                              void* d_out, int out_size, void* d_ws, size_t ws_size,
                              hipStream_t stream) {
    const float* x_c = (const float*)d_in[0];
    const float* x_m = (const float*)d_in[1];
    const int* cm_src = (const int*)d_in[2];
    const int* cm_dst = (const int*)d_in[3];
    const int* mc_src = (const int*)d_in[4];
    const int* mc_dst = (const int*)d_in[5];
    const float* Wl1_cm = (const float*)d_in[6];
    const float* Wr1_cm = (const float*)d_in[7];
    const float* b1_cm = (const float*)d_in[8];
    const float* Wl1_mc = (const float*)d_in[9];
    const float* Wr1_mc = (const float*)d_in[10];
    const float* b1_mc = (const float*)d_in[11];
    // layer-2 cm weights (d_in[12..14]) are dead: h2_m is unused in the reference
    const float* Wl2_mc = (const float*)d_in[15];
    const float* Wr2_mc = (const float*)d_in[16];
    const float* b2_mc = (const float*)d_in[17];
    const float* W_lin = (const float*)d_in[18];
    const float* b_lin = (const float*)d_in[19];
    float* out = (float*)d_out;

    // ---- workspace layout ----
    float* ws = (float*)d_ws;
    float* h_m = ws;
    float* h_c = h_m + (long)NM * DF;
    int* ip = (int*)(h_c + (long)NC * DF);
    int* binsM = ip;
    int* binsC = binsM + NM;
    int* curM = binsC + NC;
    int* curC = curM + NM;
    int* startM = curC + NC;
    int* startC = startM + (NM + 1);
    int* srt_cm = startC + (NC + 1);
    int* srt_mc = srt_cm + NE;
    int* partM = srt_mc + NE;
    int* boffM = partM + SCAN_B;
    int* partC = boffM + SCAN_B;
    int* boffC = partC + SCAN_B;

    // zero bins + cursors (contiguous), and the atomically-accumulated output
    hipMemsetAsync(binsM, 0, (size_t)(2 * (NM + NC)) * sizeof(int), stream);
    hipMemsetAsync(out, 0, (size_t)out_size * sizeof(float), stream);

    // build CSR grouping by destination for both edge types
    hist_k<<<2048, 256, 0, stream>>>(cm_dst, binsM, NE);
    hist_k<<<2048, 256, 0, stream>>>(mc_dst, binsC, NE);

    scan_part_k<<<SCAN_B, SCAN_T, 0, stream>>>(binsM, partM, NM);
    scan_mid_k<<<1, SCAN_B, 0, stream>>>(partM, boffM, startM, NM);
    scan_fin_k<<<SCAN_B, SCAN_T, 0, stream>>>(binsM, boffM, startM, NM);

    scan_part_k<<<SCAN_B, SCAN_T, 0, stream>>>(binsC, partC, NC);
    scan_mid_k<<<1, SCAN_B, 0, stream>>>(partC, boffC, startC, NC);
    scan_fin_k<<<SCAN_B, SCAN_T, 0, stream>>>(binsC, boffC, startC, NC);

    place_k<<<2048, 256, 0, stream>>>(cm_src, cm_dst, startM, curM, srt_cm, NE);
    place_k<<<2048, 256, 0, stream>>>(mc_src, mc_dst, startC, curC, srt_mc, NE);

    // layer 1 (agg fused into dense): h_m, h_c
    fused1_k<<<NM / 16, 256, 0, stream>>>(x_c, startM, srt_cm, x_m,
                                          Wl1_cm, Wr1_cm, b1_cm, h_m, NM);
    fused1_k<<<NC / 16, 256, 0, stream>>>(x_m, startC, srt_mc, x_c,
                                          Wl1_mc, Wr1_mc, b1_mc, h_c, NC);

    // layer 2 (agg of h_m over mc edges fused with dense2 + final linear)
    fused2_k<<<NC / 16, 256, 0, stream>>>(h_m, startC, srt_mc, h_c,
                                          Wl2_mc, Wr2_mc, b2_mc,
                                          W_lin, b_lin, out, NC);
}